// Round 7
// baseline (324.013 us; speedup 1.0000x reference)
//
#include <hip/hip_runtime.h>
#include <hip/hip_bf16.h>
#include <math.h>

// ---------------------------------------------------------------------------
// QGINLayer, 5 dispatches:
//   init:    hamilton->bf16 B-frags + zero counts/statsR
//   scatter: bucket scatter of edges (standalone: max occupancy)
//   gemm1:   y(bf16,ws) = x @ H1 [MFMA]
//   spmm:    out1(bf16, interleaved in d_out) = segsum(ev * y[col])
//            + fused BN stats (LDS transpose-reduce + 32-way replicated atomics)
//   gemm2:   d_out(f32) = tanh(BN(out1)) @ H2 [MFMA, bnfinal in prologue]
// ---------------------------------------------------------------------------

#define FDIM 256
#define RCAP 48   // bucket capacity per row; P(Poisson(16) > 48) ~ 1e-11
#define NREP 32   // replicated stat accumulators

typedef __attribute__((ext_vector_type(8))) short bf16x8;
typedef __attribute__((ext_vector_type(4))) float f32x4;

static __device__ inline short f2bf(float x) {
    __hip_bfloat16 h = __float2bfloat16(x);
    return *reinterpret_cast<short*>(&h);
}
static __device__ inline float bf2f(unsigned short u) {
    union { unsigned int i; float f; } c;
    c.i = ((unsigned int)u) << 16;
    return c.f;
}
static __device__ inline float bflo(unsigned int u) {
    union { unsigned int i; float f; } c;
    c.i = u << 16;
    return c.f;
}
static __device__ inline float bfhi(unsigned int u) {
    union { unsigned int i; float f; } c;
    c.i = u & 0xFFFF0000u;
    return c.f;
}
static __device__ inline float fast_tanh(float x) {
    float e = __expf(2.f * x);
    return 1.f - 2.f * __builtin_amdgcn_rcpf(e + 1.f);
}

// ---------- hamilton fragment builder (device helper) ----------
// frag f = tile*8 + kk ; element (lane, j):
//   k = kk*32 + (lane>>4)*8 + j ; col = tile*16 + (lane&15)
static __device__ void build_hfrag(const float* __restrict__ w, ushort* __restrict__ hf,
                                   int t) {
    const int   comp_t[16] = {0,1,2,3,  1,0,3,2,  2,3,0,1,  3,2,1,0};
    const float sign_t[16] = {1,1,1,1, -1,1,1,-1, -1,-1,1,1, -1,1,-1,1};
    int f = t >> 6, lane = t & 63;
    int tile = f >> 3, kk = f & 7;
    int col = tile * 16 + (lane & 15);
    int b = col >> 6, q = col & 63;
    ushort o[8];
#pragma unroll
    for (int j = 0; j < 8; ++j) {
        int k = kk * 32 + ((lane >> 4) << 3) + j;
        int a = k >> 6, p = k & 63;
        int ab = a * 4 + b;
        float v = sign_t[ab] * w[p * 256 + comp_t[ab] * 64 + q];
        o[j] = (ushort)f2bf(v);
    }
    *(ushort4*)(hf + (size_t)t * 8)     = make_ushort4(o[0], o[1], o[2], o[3]);
    *(ushort4*)(hf + (size_t)t * 8 + 4) = make_ushort4(o[4], o[5], o[6], o[7]);
}

// ---------- init: hfrag (0-63) + zero statsR (64-79) + zero counts (80+) ----------
__global__ void k_init(const float* __restrict__ w1, const float* __restrict__ w2,
                       ushort* __restrict__ h1f, ushort* __restrict__ h2f,
                       int* __restrict__ counts, float* __restrict__ statsR, int n) {
    int b = blockIdx.x;
    if (b < 32) {
        build_hfrag(w1, h1f, b * 256 + threadIdx.x);
    } else if (b < 64) {
        build_hfrag(w2, h2f, (b - 32) * 256 + threadIdx.x);
    } else if (b < 80) {
        int slot = (b - 64) * 256 + threadIdx.x;   // 4096 float4 slots
        *(float4*)(statsR + slot * 4) = make_float4(0.f, 0.f, 0.f, 0.f);
    } else {
        int idx = (b - 80) * 1024 + threadIdx.x * 4;
        if (idx < n) *(int4*)(counts + idx) = make_int4(0, 0, 0, 0);
    }
}

// ---------- bucket scatter (standalone; no LDS, minimal VGPR) ----------
__global__ void k_scatter(const int* __restrict__ rows, const int* __restrict__ cols,
                          const float* __restrict__ vals, int* __restrict__ counts,
                          unsigned int* __restrict__ ew, int E) {
    int e = blockIdx.x * 256 + threadIdx.x;
    if (e >= E) return;
    int r = rows[e];
    int slot = atomicAdd(&counts[r], 1);
    if (slot < RCAP) {
        int iv = (int)(vals[e] * 32768.0f);  // [0,1) -> 15-bit fixed point
        ew[(size_t)r * RCAP + slot] = (unsigned int)cols[e] | ((unsigned int)iv << 17);
    }
}

// ---------- GEMM1: y(bf16) = x(f32) @ H1f ; 128 rows/block, LDS-staged B ----------
__global__ __launch_bounds__(256) void k_gemm1(const float* __restrict__ X,
                                               const ushort* __restrict__ Bf,
                                               ushort* __restrict__ Y, int N) {
    __shared__ ushort lds[16384];  // 32 KB: one col-group (4 tiles x 8 kk frags)
    const int t = threadIdx.x;
    const int w = t >> 6, lane = t & 63;
    const int r0 = blockIdx.x * 128 + w * 32;
    const int kbase = ((lane >> 4) & 3) * 8;
    const int rA[2] = { min(r0 + (lane & 15), N - 1),
                        min(r0 + 16 + (lane & 15), N - 1) };

    bf16x8 af[2][8];
#pragma unroll
    for (int rt = 0; rt < 2; ++rt)
#pragma unroll
        for (int kk = 0; kk < 8; ++kk) {
            const float* p = X + (size_t)rA[rt] * 256 + kk * 32 + kbase;
            float4 v0 = *(const float4*)p;
            float4 v1 = *(const float4*)(p + 4);
            bf16x8 a;
            a[0] = f2bf(v0.x); a[1] = f2bf(v0.y); a[2] = f2bf(v0.z); a[3] = f2bf(v0.w);
            a[4] = f2bf(v1.x); a[5] = f2bf(v1.y); a[6] = f2bf(v1.z); a[7] = f2bf(v1.w);
            af[rt][kk] = a;
        }

    for (int g = 0; g < 4; ++g) {
        {
            const float4* s4 = (const float4*)(Bf + (size_t)g * 16384 + t * 64);
            float4* d4 = (float4*)(lds + t * 64);
#pragma unroll
            for (int i = 0; i < 8; ++i) d4[i] = s4[i];
        }
        __syncthreads();

        f32x4 acc[2][4];
#pragma unroll
        for (int rt = 0; rt < 2; ++rt)
#pragma unroll
            for (int tg = 0; tg < 4; ++tg) acc[rt][tg] = (f32x4){0.f, 0.f, 0.f, 0.f};

#pragma unroll
        for (int tg = 0; tg < 4; ++tg)
#pragma unroll
            for (int kk = 0; kk < 8; ++kk) {
                bf16x8 b = *(const bf16x8*)(lds + ((tg * 8 + kk) * 64 + lane) * 8);
                acc[0][tg] = __builtin_amdgcn_mfma_f32_16x16x32_bf16(af[0][kk], b, acc[0][tg], 0, 0, 0);
                acc[1][tg] = __builtin_amdgcn_mfma_f32_16x16x32_bf16(af[1][kk], b, acc[1][tg], 0, 0, 0);
            }

#pragma unroll
        for (int tg = 0; tg < 4; ++tg) {
            int col = (g * 4 + tg) * 16 + (lane & 15);
#pragma unroll
            for (int rt = 0; rt < 2; ++rt) {
                int rbase = r0 + rt * 16 + ((lane >> 4) & 3) * 4;
#pragma unroll
                for (int j = 0; j < 4; ++j) {
                    int r = rbase + j;
                    if (r < N) Y[(size_t)r * 256 + col] = (ushort)f2bf(acc[rt][tg][j]);
                }
            }
        }
        __syncthreads();
    }
}

// ---------- SpMM gather + fused stats: 2 rows/wave, half-wave split, unroll-8 ----------
__global__ __launch_bounds__(256) void k_spmm(const ushort* __restrict__ Y,
                                              const int* __restrict__ counts,
                                              const unsigned int* __restrict__ ew,
                                              ushort* __restrict__ O,
                                              float* __restrict__ statsR, int n) {
    __shared__ float ls[8][256];
    const int tid = threadIdx.x;
    int wid = (blockIdx.x * blockDim.x + tid) >> 6;
    int w = tid >> 6, lane = tid & 63;
    int l32 = lane & 31;
    int row = wid * 2 + (lane >> 5);
    bool ok = row < n;
    int r = ok ? row : 0;
    int cnt = ok ? min(counts[r], RCAP) : 0;
    int g = (cnt + 7) >> 3;
    const unsigned int* ep = ew + (size_t)r * RCAP;

    float a0 = 0.f, a1 = 0.f, a2 = 0.f, a3 = 0.f;
    float a4 = 0.f, a5 = 0.f, a6 = 0.f, a7 = 0.f;

    unsigned int wv[8];
    if (g > 0) {
#pragma unroll
        for (int i = 0; i < 8; ++i) wv[i] = ep[i];
    }
    for (int gi = 0; gi < g; ++gi) {
        unsigned int wn[8];
        bool more = (gi + 1) < g;
        if (more) {
#pragma unroll
            for (int i = 0; i < 8; ++i) wn[i] = ep[(gi + 1) * 8 + i];
        }
#pragma unroll
        for (int i = 0; i < 8; ++i) {
            int idx = gi * 8 + i;
            unsigned int wd = wv[i];
            int c = (idx < cnt) ? (int)(wd & 0x1FFFFu) : 0;
            float v = (idx < cnt) ? (float)(wd >> 17) * (1.0f / 32768.0f) : 0.f;
            uint4 u = *(const uint4*)(Y + (size_t)c * 256 + l32 * 8);
            a0 = fmaf(v, bflo(u.x), a0); a1 = fmaf(v, bfhi(u.x), a1);
            a2 = fmaf(v, bflo(u.y), a2); a3 = fmaf(v, bfhi(u.y), a3);
            a4 = fmaf(v, bflo(u.z), a4); a5 = fmaf(v, bfhi(u.z), a5);
            a6 = fmaf(v, bflo(u.w), a6); a7 = fmaf(v, bfhi(u.w), a7);
        }
        if (more) {
#pragma unroll
            for (int i = 0; i < 8; ++i) wv[i] = wn[i];
        }
    }
    if (ok) {
        unsigned int p0 = ((unsigned int)(unsigned short)f2bf(a0)) |
                          (((unsigned int)(unsigned short)f2bf(a1)) << 16);
        unsigned int p1 = ((unsigned int)(unsigned short)f2bf(a2)) |
                          (((unsigned int)(unsigned short)f2bf(a3)) << 16);
        unsigned int p2 = ((unsigned int)(unsigned short)f2bf(a4)) |
                          (((unsigned int)(unsigned short)f2bf(a5)) << 16);
        unsigned int p3 = ((unsigned int)(unsigned short)f2bf(a6)) |
                          (((unsigned int)(unsigned short)f2bf(a7)) << 16);
        *(uint4*)(O + (size_t)r * 512 + l32 * 8) = make_uint4(p0, p1, p2, p3);
    }

    // ---- fused BN stats: LDS transpose-reduce, then replicated global atomics ----
    int h2 = w * 2 + (lane >> 5);    // stream 0..7
    int fb = l32 * 8;                // feature base
    int rep = blockIdx.x & (NREP - 1);
    *(float4*)&ls[h2][fb]     = make_float4(a0, a1, a2, a3);
    *(float4*)&ls[h2][fb + 4] = make_float4(a4, a5, a6, a7);
    __syncthreads();
    float sv = 0.f;
#pragma unroll
    for (int i = 0; i < 8; ++i) sv += ls[i][tid];
    atomicAdd(&statsR[rep * 256 + tid], sv);
    __syncthreads();
    *(float4*)&ls[h2][fb]     = make_float4(a0 * a0, a1 * a1, a2 * a2, a3 * a3);
    *(float4*)&ls[h2][fb + 4] = make_float4(a4 * a4, a5 * a5, a6 * a6, a7 * a7);
    __syncthreads();
    float qv = 0.f;
#pragma unroll
    for (int i = 0; i < 8; ++i) qv += ls[i][tid];
    atomicAdd(&statsR[NREP * 256 + rep * 256 + tid], qv);
}

// ---------- GEMM2: d_out(f32,in-place) = tanh(BN(out1)) @ H2f ----------
__global__ __launch_bounds__(256) void k_gemm2(void* __restrict__ Av,
                                               const ushort* __restrict__ Bf,
                                               const float* __restrict__ statsR,
                                               const float* __restrict__ gamma,
                                               const float* __restrict__ beta, int N) {
    __shared__ ushort lds[16384];
    __shared__ float sscl[256], sshf[256];
    const int t = threadIdx.x;
    const int w = t >> 6, lane = t & 63;
    const int r0 = blockIdx.x * 128 + w * 32;
    const int kbase = ((lane >> 4) & 3) * 8;
    const int rA[2] = { min(r0 + (lane & 15), N - 1),
                        min(r0 + 16 + (lane & 15), N - 1) };

    {   // fused bnfinal: reduce NREP replicas, compute scale/shift
        float s = 0.f, q = 0.f;
#pragma unroll
        for (int i = 0; i < NREP; ++i) {
            s += statsR[i * 256 + t];
            q += statsR[NREP * 256 + i * 256 + t];
        }
        float invn = 1.0f / (float)N;
        float mean = s * invn;
        float var = q * invn - mean * mean;
        float inv = rsqrtf(var + 1e-5f);
        float gg = gamma[t] * inv;
        sscl[t] = gg;
        sshf[t] = beta[t] - mean * gg;
        __syncthreads();
    }

    const ushort* X = (const ushort*)Av;  // row stride 512 ushorts
    bf16x8 af[2][8];
#pragma unroll
    for (int rt = 0; rt < 2; ++rt)
#pragma unroll
        for (int kk = 0; kk < 8; ++kk) {
            const ushort* p = X + (size_t)rA[rt] * 512 + kk * 32 + kbase;
            ushort4 u0 = *(const ushort4*)p;
            ushort4 u1 = *(const ushort4*)(p + 4);
            float4 s0 = *(const float4*)&sscl[kk * 32 + kbase];
            float4 s1 = *(const float4*)&sscl[kk * 32 + kbase + 4];
            float4 h0 = *(const float4*)&sshf[kk * 32 + kbase];
            float4 h1 = *(const float4*)&sshf[kk * 32 + kbase + 4];
            bf16x8 a;
            a[0] = f2bf(fast_tanh(fmaf(bf2f(u0.x), s0.x, h0.x)));
            a[1] = f2bf(fast_tanh(fmaf(bf2f(u0.y), s0.y, h0.y)));
            a[2] = f2bf(fast_tanh(fmaf(bf2f(u0.z), s0.z, h0.z)));
            a[3] = f2bf(fast_tanh(fmaf(bf2f(u0.w), s0.w, h0.w)));
            a[4] = f2bf(fast_tanh(fmaf(bf2f(u1.x), s1.x, h1.x)));
            a[5] = f2bf(fast_tanh(fmaf(bf2f(u1.y), s1.y, h1.y)));
            a[6] = f2bf(fast_tanh(fmaf(bf2f(u1.z), s1.z, h1.z)));
            a[7] = f2bf(fast_tanh(fmaf(bf2f(u1.w), s1.w, h1.w)));
            af[rt][kk] = a;
        }

    float* Cf = (float*)Av;
    for (int g = 0; g < 4; ++g) {
        {
            const float4* s4 = (const float4*)(Bf + (size_t)g * 16384 + t * 64);
            float4* d4 = (float4*)(lds + t * 64);
#pragma unroll
            for (int i = 0; i < 8; ++i) d4[i] = s4[i];
        }
        __syncthreads();  // drains vmcnt: all A-loads in regs before stores below

        f32x4 acc[2][4];
#pragma unroll
        for (int rt = 0; rt < 2; ++rt)
#pragma unroll
            for (int tg = 0; tg < 4; ++tg) acc[rt][tg] = (f32x4){0.f, 0.f, 0.f, 0.f};

#pragma unroll
        for (int tg = 0; tg < 4; ++tg)
#pragma unroll
            for (int kk = 0; kk < 8; ++kk) {
                bf16x8 b = *(const bf16x8*)(lds + ((tg * 8 + kk) * 64 + lane) * 8);
                acc[0][tg] = __builtin_amdgcn_mfma_f32_16x16x32_bf16(af[0][kk], b, acc[0][tg], 0, 0, 0);
                acc[1][tg] = __builtin_amdgcn_mfma_f32_16x16x32_bf16(af[1][kk], b, acc[1][tg], 0, 0, 0);
            }

#pragma unroll
        for (int tg = 0; tg < 4; ++tg) {
            int col = (g * 4 + tg) * 16 + (lane & 15);
#pragma unroll
            for (int rt = 0; rt < 2; ++rt) {
                int rbase = r0 + rt * 16 + ((lane >> 4) & 3) * 4;
#pragma unroll
                for (int j = 0; j < 4; ++j) {
                    int r = rbase + j;
                    if (r < N) Cf[(size_t)r * 256 + col] = acc[rt][tg][j];
                }
            }
        }
        __syncthreads();
    }
}

extern "C" void kernel_launch(void* const* d_in, const int* in_sizes, int n_in,
                              void* d_out, int out_size, void* d_ws, size_t ws_size,
                              hipStream_t stream) {
    const float* x     = (const float*)d_in[0];
    const int* rows    = (const int*)d_in[1];
    const int* cols    = (const int*)d_in[2];
    const float* evin  = (const float*)d_in[3];
    const float* w1    = (const float*)d_in[4];
    const float* w2    = (const float*)d_in[5];
    const float* gamma = (const float*)d_in[6];
    const float* beta  = (const float*)d_in[7];
    float* out = (float*)d_out;

    const int N = in_sizes[0] / FDIM;  // 100000
    const int E = in_sizes[1];         // 1600000

    char* ws = (char*)d_ws;
    size_t o = 0;
    auto alloc = [&](size_t bytes) -> char* {
        char* p = ws + o;
        o += (bytes + 255) & ~(size_t)255;
        return p;
    };
    ushort* h1f = (ushort*)alloc(128 * 64 * 8 * 2);
    ushort* h2f = (ushort*)alloc(128 * 64 * 8 * 2);
    ushort* y   = (ushort*)alloc((size_t)N * 256 * 2);              // 51.2 MB
    int*    counts = (int*)alloc((size_t)N * 4);
    float*  statsR = (float*)alloc(2 * NREP * 256 * 4);             // 64 KB
    unsigned int* ew = (unsigned int*)alloc((size_t)N * RCAP * 4);  // 19.2 MB

    // init: hfrag (64) + zero statsR (16) + zero counts (98)
    int zblk = (N + 1023) / 1024;
    k_init<<<80 + zblk, 256, 0, stream>>>(w1, w2, h1f, h2f, counts, statsR, N);

    // bucket scatter (standalone, high occupancy)
    k_scatter<<<(E + 255) / 256, 256, 0, stream>>>(rows, cols, evin, counts, ew, E);

    int gblk = (N + 127) / 128;  // 782
    // y = x @ H1 (bf16)
    k_gemm1<<<gblk, 256, 0, stream>>>(x, h1f, y, N);
    // out1(bf16, interleaved in d_out) = segsum(ev * y[col]) + BN stats
    int waves = (N + 1) / 2;
    k_spmm<<<(waves * 64 + 255) / 256, 256, 0, stream>>>(y, counts, ew,
                                                         (ushort*)out, statsR, N);
    // d_out(f32) = tanh(BN(out1)) @ H2  (bnfinal reduces statsR in prologue)
    k_gemm2<<<gblk, 256, 0, stream>>>(out, h2f, statsR, gamma, beta, N);
}

// Round 8
// 295.015 us; speedup vs baseline: 1.0983x; 1.0983x over previous
//
#include <hip/hip_runtime.h>
#include <hip/hip_bf16.h>
#include <math.h>

// ---------------------------------------------------------------------------
// QGINLayer, 8 dispatches, ZERO global atomics in CSR build:
//   init:  hamilton->bf16 B-frags + zero statsR
//   p1:    per-chunk LDS histogram of coarse buckets (row>>9)  -> CM
//   p2:    per-bucket scan over chunks -> PO, totals BT
//   p3:    per-chunk LDS-rank scatter -> tmp2 (bucket-grouped (col|val,row))
//   p4:    per-bucket LDS hist+scan -> CSR offs + row-grouped ew
//   gemm1: y(bf16,ws) = x @ H1 [MFMA]
//   spmm:  out1(bf16, interleaved in d_out) = segsum(ev*y[col]) + BN stats
//   gemm2: d_out(f32) = tanh(BN(out1)) @ H2 [MFMA, bnfinal in prologue]
// ---------------------------------------------------------------------------

#define FDIM 256
#define NREP 32     // replicated stat accumulators
#define CH 2048     // edges per chunk in binning

typedef __attribute__((ext_vector_type(8))) short bf16x8;
typedef __attribute__((ext_vector_type(4))) float f32x4;

static __device__ inline short f2bf(float x) {
    __hip_bfloat16 h = __float2bfloat16(x);
    return *reinterpret_cast<short*>(&h);
}
static __device__ inline float bf2f(unsigned short u) {
    union { unsigned int i; float f; } c;
    c.i = ((unsigned int)u) << 16;
    return c.f;
}
static __device__ inline float bflo(unsigned int u) {
    union { unsigned int i; float f; } c;
    c.i = u << 16;
    return c.f;
}
static __device__ inline float bfhi(unsigned int u) {
    union { unsigned int i; float f; } c;
    c.i = u & 0xFFFF0000u;
    return c.f;
}
static __device__ inline float fast_tanh(float x) {
    float e = __expf(2.f * x);
    return 1.f - 2.f * __builtin_amdgcn_rcpf(e + 1.f);
}

// ---------- hamilton fragment builder ----------
static __device__ void build_hfrag(const float* __restrict__ w, ushort* __restrict__ hf,
                                   int t) {
    const int   comp_t[16] = {0,1,2,3,  1,0,3,2,  2,3,0,1,  3,2,1,0};
    const float sign_t[16] = {1,1,1,1, -1,1,1,-1, -1,-1,1,1, -1,1,-1,1};
    int f = t >> 6, lane = t & 63;
    int tile = f >> 3, kk = f & 7;
    int col = tile * 16 + (lane & 15);
    int b = col >> 6, q = col & 63;
    ushort o[8];
#pragma unroll
    for (int j = 0; j < 8; ++j) {
        int k = kk * 32 + ((lane >> 4) << 3) + j;
        int a = k >> 6, p = k & 63;
        int ab = a * 4 + b;
        float v = sign_t[ab] * w[p * 256 + comp_t[ab] * 64 + q];
        o[j] = (ushort)f2bf(v);
    }
    *(ushort4*)(hf + (size_t)t * 8)     = make_ushort4(o[0], o[1], o[2], o[3]);
    *(ushort4*)(hf + (size_t)t * 8 + 4) = make_ushort4(o[4], o[5], o[6], o[7]);
}

// ---------- init: hfrag (0-63) + zero statsR (64-79) ----------
__global__ void k_init(const float* __restrict__ w1, const float* __restrict__ w2,
                       ushort* __restrict__ h1f, ushort* __restrict__ h2f,
                       float* __restrict__ statsR) {
    int b = blockIdx.x;
    if (b < 32) {
        build_hfrag(w1, h1f, b * 256 + threadIdx.x);
    } else if (b < 64) {
        build_hfrag(w2, h2f, (b - 32) * 256 + threadIdx.x);
    } else {
        int slot = (b - 64) * 256 + threadIdx.x;   // 4096 float4 slots = 64 KB
        *(float4*)(statsR + slot * 4) = make_float4(0.f, 0.f, 0.f, 0.f);
    }
}

// ---------- P1: per-chunk coarse histogram (LDS atomics only) ----------
__global__ __launch_bounds__(256) void k_p1(const int* __restrict__ rows,
                                            int* __restrict__ CM,
                                            int E, int nchunk, int NB) {
    __shared__ int lc[256];
    int t = threadIdx.x, c = blockIdx.x;
    lc[t] = 0;
    __syncthreads();
#pragma unroll
    for (int i = 0; i < 8; ++i) {
        int e = c * CH + i * 256 + t;
        if (e < E) atomicAdd(&lc[rows[e] >> 9], 1);
    }
    __syncthreads();
    if (t < NB) CM[t * nchunk + c] = lc[t];
}

// ---------- P2: per-bucket exclusive scan over chunks ----------
__global__ __launch_bounds__(256) void k_p2(const int* __restrict__ CM,
                                            int* __restrict__ PO,
                                            int* __restrict__ BT, int nchunk) {
    __shared__ int ts[256];
    int t = threadIdx.x, b = blockIdx.x;
    int base = b * nchunk;
    int lex[4], s = 0;
#pragma unroll
    for (int i = 0; i < 4; ++i) {
        int c = t * 4 + i;
        int v = (c < nchunk) ? CM[base + c] : 0;
        lex[i] = s;
        s += v;
    }
    ts[t] = s;
    __syncthreads();
    for (int off = 1; off < 256; off <<= 1) {
        int v = (t >= off) ? ts[t - off] : 0;
        __syncthreads();
        ts[t] += v;
        __syncthreads();
    }
    int excl = ts[t] - s;
#pragma unroll
    for (int i = 0; i < 4; ++i) {
        int c = t * 4 + i;
        if (c < nchunk) PO[base + c] = excl + lex[i];
    }
    if (t == 255) BT[b] = ts[255];
}

// ---------- P3: per-chunk rank-scatter into bucket-grouped tmp2 ----------
__global__ __launch_bounds__(256) void k_p3(const int* __restrict__ rows,
                                            const int* __restrict__ cols,
                                            const float* __restrict__ vals,
                                            const int* __restrict__ PO,
                                            const int* __restrict__ BT,
                                            uint2* __restrict__ tmp2,
                                            int E, int nchunk, int NB) {
    __shared__ int sBB[256];
    __shared__ int sPO[256];
    __shared__ int sLC[256];
    int t = threadIdx.x, c = blockIdx.x;
    int own = (t < NB) ? BT[t] : 0;
    sBB[t] = own;
    sPO[t] = (t < NB) ? PO[t * nchunk + c] : 0;
    sLC[t] = 0;
    __syncthreads();
    for (int off = 1; off < 256; off <<= 1) {
        int v = (t >= off) ? sBB[t - off] : 0;
        __syncthreads();
        sBB[t] += v;
        __syncthreads();
    }
    sBB[t] -= own;  // exclusive
    __syncthreads();
#pragma unroll
    for (int i = 0; i < 8; ++i) {
        int e = c * CH + i * 256 + t;
        if (e < E) {
            int r = rows[e];
            int b = r >> 9;
            int rank = atomicAdd(&sLC[b], 1);
            int pos = sBB[b] + sPO[b] + rank;
            int iv = (int)(vals[e] * 32768.0f);
            tmp2[pos] = make_uint2((unsigned int)cols[e] | ((unsigned int)iv << 17),
                                   (unsigned int)r);
        }
    }
}

// ---------- P4: per-bucket row sort -> CSR offs + packed ew ----------
__global__ __launch_bounds__(1024) void k_p4(const uint2* __restrict__ tmp2,
                                             const int* __restrict__ BT,
                                             unsigned int* __restrict__ ew,
                                             int* __restrict__ offs,
                                             int N, int NB) {
    __shared__ int sBB[256];
    __shared__ int sH[512];
    __shared__ int sO[512];
    __shared__ int sC[512];
    int t = threadIdx.x, b = blockIdx.x;
    int own = 0;
    if (t < 256) {
        own = (t < NB) ? BT[t] : 0;
        sBB[t] = own;
    }
    __syncthreads();
    for (int off = 1; off < 256; off <<= 1) {
        int v = (t < 256 && t >= off) ? sBB[t - off] : 0;
        __syncthreads();
        if (t < 256) sBB[t] += v;
        __syncthreads();
    }
    if (t < 256) sBB[t] -= own;
    if (t < 512) sH[t] = 0;
    __syncthreads();
    const int base = sBB[b];
    const int nE = BT[b];
    const int rbase = b << 9;
    for (int i = t; i < nE; i += 1024)
        atomicAdd(&sH[(int)tmp2[base + i].y - rbase], 1);
    __syncthreads();
    if (t < 512) sO[t] = sH[t];
    __syncthreads();
    for (int off = 1; off < 512; off <<= 1) {
        int v = (t < 512 && t >= off) ? sO[t - off] : 0;
        __syncthreads();
        if (t < 512) sO[t] += v;
        __syncthreads();
    }
    if (t < 512) {
        sO[t] -= sH[t];  // exclusive within bucket
        int r = rbase + t;
        if (r <= N) offs[r] = base + sO[t];
        sC[t] = 0;
    }
    __syncthreads();
    for (int i = t; i < nE; i += 1024) {
        uint2 u = tmp2[base + i];
        int lr = (int)u.y - rbase;
        int p = atomicAdd(&sC[lr], 1);
        ew[base + sO[lr] + p] = u.x;
    }
}

// ---------- GEMM1: y(bf16) = x(f32) @ H1f ----------
__global__ __launch_bounds__(256) void k_gemm1(const float* __restrict__ X,
                                               const ushort* __restrict__ Bf,
                                               ushort* __restrict__ Y, int N) {
    __shared__ ushort lds[16384];
    const int t = threadIdx.x;
    const int w = t >> 6, lane = t & 63;
    const int r0 = blockIdx.x * 128 + w * 32;
    const int kbase = ((lane >> 4) & 3) * 8;
    const int rA[2] = { min(r0 + (lane & 15), N - 1),
                        min(r0 + 16 + (lane & 15), N - 1) };

    bf16x8 af[2][8];
#pragma unroll
    for (int rt = 0; rt < 2; ++rt)
#pragma unroll
        for (int kk = 0; kk < 8; ++kk) {
            const float* p = X + (size_t)rA[rt] * 256 + kk * 32 + kbase;
            float4 v0 = *(const float4*)p;
            float4 v1 = *(const float4*)(p + 4);
            bf16x8 a;
            a[0] = f2bf(v0.x); a[1] = f2bf(v0.y); a[2] = f2bf(v0.z); a[3] = f2bf(v0.w);
            a[4] = f2bf(v1.x); a[5] = f2bf(v1.y); a[6] = f2bf(v1.z); a[7] = f2bf(v1.w);
            af[rt][kk] = a;
        }

    for (int g = 0; g < 4; ++g) {
        {
            const float4* s4 = (const float4*)(Bf + (size_t)g * 16384 + t * 64);
            float4* d4 = (float4*)(lds + t * 64);
#pragma unroll
            for (int i = 0; i < 8; ++i) d4[i] = s4[i];
        }
        __syncthreads();

        f32x4 acc[2][4];
#pragma unroll
        for (int rt = 0; rt < 2; ++rt)
#pragma unroll
            for (int tg = 0; tg < 4; ++tg) acc[rt][tg] = (f32x4){0.f, 0.f, 0.f, 0.f};

#pragma unroll
        for (int tg = 0; tg < 4; ++tg)
#pragma unroll
            for (int kk = 0; kk < 8; ++kk) {
                bf16x8 b = *(const bf16x8*)(lds + ((tg * 8 + kk) * 64 + lane) * 8);
                acc[0][tg] = __builtin_amdgcn_mfma_f32_16x16x32_bf16(af[0][kk], b, acc[0][tg], 0, 0, 0);
                acc[1][tg] = __builtin_amdgcn_mfma_f32_16x16x32_bf16(af[1][kk], b, acc[1][tg], 0, 0, 0);
            }

#pragma unroll
        for (int tg = 0; tg < 4; ++tg) {
            int col = (g * 4 + tg) * 16 + (lane & 15);
#pragma unroll
            for (int rt = 0; rt < 2; ++rt) {
                int rbase = r0 + rt * 16 + ((lane >> 4) & 3) * 4;
#pragma unroll
                for (int j = 0; j < 4; ++j) {
                    int r = rbase + j;
                    if (r < N) Y[(size_t)r * 256 + col] = (ushort)f2bf(acc[rt][tg][j]);
                }
            }
        }
        __syncthreads();
    }
}

// ---------- SpMM (CSR) + fused stats: 2 rows/wave, batched 8-gather ----------
__global__ __launch_bounds__(256) void k_spmm(const ushort* __restrict__ Y,
                                              const int* __restrict__ offs,
                                              const unsigned int* __restrict__ ew,
                                              ushort* __restrict__ O,
                                              float* __restrict__ statsR, int n) {
    __shared__ float ls[8][256];
    const int tid = threadIdx.x;
    int wid = (blockIdx.x * blockDim.x + tid) >> 6;
    int w = tid >> 6, lane = tid & 63;
    int l32 = lane & 31;
    int row = wid * 2 + (lane >> 5);
    bool ok = row < n;
    int r = ok ? row : 0;
    int beg = offs[r];
    int cnt = ok ? (offs[r + 1] - beg) : 0;
    int g = (cnt + 7) >> 3;
    const unsigned int* ep = ew + beg;

    float a0 = 0.f, a1 = 0.f, a2 = 0.f, a3 = 0.f;
    float a4 = 0.f, a5 = 0.f, a6 = 0.f, a7 = 0.f;

    for (int gi = 0; gi < g; ++gi) {
        unsigned int wv[8];
#pragma unroll
        for (int i = 0; i < 8; ++i) wv[i] = ep[gi * 8 + i];  // +8 slack alloc
        uint4 u[8];
#pragma unroll
        for (int i = 0; i < 8; ++i) {
            int c = (gi * 8 + i < cnt) ? (int)(wv[i] & 0x1FFFFu) : 0;
            u[i] = *(const uint4*)(Y + (size_t)c * 256 + l32 * 8);
        }
#pragma unroll
        for (int i = 0; i < 8; ++i) {
            float v = (gi * 8 + i < cnt) ? (float)(wv[i] >> 17) * (1.0f / 32768.0f) : 0.f;
            a0 = fmaf(v, bflo(u[i].x), a0); a1 = fmaf(v, bfhi(u[i].x), a1);
            a2 = fmaf(v, bflo(u[i].y), a2); a3 = fmaf(v, bfhi(u[i].y), a3);
            a4 = fmaf(v, bflo(u[i].z), a4); a5 = fmaf(v, bfhi(u[i].z), a5);
            a6 = fmaf(v, bflo(u[i].w), a6); a7 = fmaf(v, bfhi(u[i].w), a7);
        }
    }
    if (ok) {
        unsigned int p0 = ((unsigned int)(unsigned short)f2bf(a0)) |
                          (((unsigned int)(unsigned short)f2bf(a1)) << 16);
        unsigned int p1 = ((unsigned int)(unsigned short)f2bf(a2)) |
                          (((unsigned int)(unsigned short)f2bf(a3)) << 16);
        unsigned int p2 = ((unsigned int)(unsigned short)f2bf(a4)) |
                          (((unsigned int)(unsigned short)f2bf(a5)) << 16);
        unsigned int p3 = ((unsigned int)(unsigned short)f2bf(a6)) |
                          (((unsigned int)(unsigned short)f2bf(a7)) << 16);
        *(uint4*)(O + (size_t)r * 512 + l32 * 8) = make_uint4(p0, p1, p2, p3);
    }

    // ---- fused BN stats: LDS transpose-reduce + replicated global atomics ----
    int h2 = w * 2 + (lane >> 5);
    int fb = l32 * 8;
    int rep = blockIdx.x & (NREP - 1);
    *(float4*)&ls[h2][fb]     = make_float4(a0, a1, a2, a3);
    *(float4*)&ls[h2][fb + 4] = make_float4(a4, a5, a6, a7);
    __syncthreads();
    float sv = 0.f;
#pragma unroll
    for (int i = 0; i < 8; ++i) sv += ls[i][tid];
    atomicAdd(&statsR[rep * 256 + tid], sv);
    __syncthreads();
    *(float4*)&ls[h2][fb]     = make_float4(a0 * a0, a1 * a1, a2 * a2, a3 * a3);
    *(float4*)&ls[h2][fb + 4] = make_float4(a4 * a4, a5 * a5, a6 * a6, a7 * a7);
    __syncthreads();
    float qv = 0.f;
#pragma unroll
    for (int i = 0; i < 8; ++i) qv += ls[i][tid];
    atomicAdd(&statsR[NREP * 256 + rep * 256 + tid], qv);
}

// ---------- GEMM2: d_out(f32,in-place) = tanh(BN(out1)) @ H2f ----------
__global__ __launch_bounds__(256) void k_gemm2(void* __restrict__ Av,
                                               const ushort* __restrict__ Bf,
                                               const float* __restrict__ statsR,
                                               const float* __restrict__ gamma,
                                               const float* __restrict__ beta, int N) {
    __shared__ ushort lds[16384];
    __shared__ float sscl[256], sshf[256];
    const int t = threadIdx.x;
    const int w = t >> 6, lane = t & 63;
    const int r0 = blockIdx.x * 128 + w * 32;
    const int kbase = ((lane >> 4) & 3) * 8;
    const int rA[2] = { min(r0 + (lane & 15), N - 1),
                        min(r0 + 16 + (lane & 15), N - 1) };

    {
        float s = 0.f, q = 0.f;
#pragma unroll
        for (int i = 0; i < NREP; ++i) {
            s += statsR[i * 256 + t];
            q += statsR[NREP * 256 + i * 256 + t];
        }
        float invn = 1.0f / (float)N;
        float mean = s * invn;
        float var = q * invn - mean * mean;
        float inv = rsqrtf(var + 1e-5f);
        float gg = gamma[t] * inv;
        sscl[t] = gg;
        sshf[t] = beta[t] - mean * gg;
        __syncthreads();
    }

    const ushort* X = (const ushort*)Av;
    bf16x8 af[2][8];
#pragma unroll
    for (int rt = 0; rt < 2; ++rt)
#pragma unroll
        for (int kk = 0; kk < 8; ++kk) {
            const ushort* p = X + (size_t)rA[rt] * 512 + kk * 32 + kbase;
            ushort4 u0 = *(const ushort4*)p;
            ushort4 u1 = *(const ushort4*)(p + 4);
            float4 s0 = *(const float4*)&sscl[kk * 32 + kbase];
            float4 s1 = *(const float4*)&sscl[kk * 32 + kbase + 4];
            float4 h0 = *(const float4*)&sshf[kk * 32 + kbase];
            float4 h1 = *(const float4*)&sshf[kk * 32 + kbase + 4];
            bf16x8 a;
            a[0] = f2bf(fast_tanh(fmaf(bf2f(u0.x), s0.x, h0.x)));
            a[1] = f2bf(fast_tanh(fmaf(bf2f(u0.y), s0.y, h0.y)));
            a[2] = f2bf(fast_tanh(fmaf(bf2f(u0.z), s0.z, h0.z)));
            a[3] = f2bf(fast_tanh(fmaf(bf2f(u0.w), s0.w, h0.w)));
            a[4] = f2bf(fast_tanh(fmaf(bf2f(u1.x), s1.x, h1.x)));
            a[5] = f2bf(fast_tanh(fmaf(bf2f(u1.y), s1.y, h1.y)));
            a[6] = f2bf(fast_tanh(fmaf(bf2f(u1.z), s1.z, h1.z)));
            a[7] = f2bf(fast_tanh(fmaf(bf2f(u1.w), s1.w, h1.w)));
            af[rt][kk] = a;
        }

    float* Cf = (float*)Av;
    for (int g = 0; g < 4; ++g) {
        {
            const float4* s4 = (const float4*)(Bf + (size_t)g * 16384 + t * 64);
            float4* d4 = (float4*)(lds + t * 64);
#pragma unroll
            for (int i = 0; i < 8; ++i) d4[i] = s4[i];
        }
        __syncthreads();

        f32x4 acc[2][4];
#pragma unroll
        for (int rt = 0; rt < 2; ++rt)
#pragma unroll
            for (int tg = 0; tg < 4; ++tg) acc[rt][tg] = (f32x4){0.f, 0.f, 0.f, 0.f};

#pragma unroll
        for (int tg = 0; tg < 4; ++tg)
#pragma unroll
            for (int kk = 0; kk < 8; ++kk) {
                bf16x8 b = *(const bf16x8*)(lds + ((tg * 8 + kk) * 64 + lane) * 8);
                acc[0][tg] = __builtin_amdgcn_mfma_f32_16x16x32_bf16(af[0][kk], b, acc[0][tg], 0, 0, 0);
                acc[1][tg] = __builtin_amdgcn_mfma_f32_16x16x32_bf16(af[1][kk], b, acc[1][tg], 0, 0, 0);
            }

#pragma unroll
        for (int tg = 0; tg < 4; ++tg) {
            int col = (g * 4 + tg) * 16 + (lane & 15);
#pragma unroll
            for (int rt = 0; rt < 2; ++rt) {
                int rbase = r0 + rt * 16 + ((lane >> 4) & 3) * 4;
#pragma unroll
                for (int j = 0; j < 4; ++j) {
                    int r = rbase + j;
                    if (r < N) Cf[(size_t)r * 256 + col] = acc[rt][tg][j];
                }
            }
        }
        __syncthreads();
    }
}

extern "C" void kernel_launch(void* const* d_in, const int* in_sizes, int n_in,
                              void* d_out, int out_size, void* d_ws, size_t ws_size,
                              hipStream_t stream) {
    const float* x     = (const float*)d_in[0];
    const int* rows    = (const int*)d_in[1];
    const int* cols    = (const int*)d_in[2];
    const float* evin  = (const float*)d_in[3];
    const float* w1    = (const float*)d_in[4];
    const float* w2    = (const float*)d_in[5];
    const float* gamma = (const float*)d_in[6];
    const float* beta  = (const float*)d_in[7];
    float* out = (float*)d_out;

    const int N = in_sizes[0] / FDIM;       // 100000
    const int E = in_sizes[1];              // 1600000
    const int NB = (N + 511) >> 9;          // 196 coarse buckets
    const int nchunk = (E + CH - 1) / CH;   // 782

    char* ws = (char*)d_ws;
    size_t o = 0;
    auto alloc = [&](size_t bytes) -> char* {
        char* p = ws + o;
        o += (bytes + 255) & ~(size_t)255;
        return p;
    };
    ushort* h1f  = (ushort*)alloc(128 * 64 * 8 * 2);
    ushort* h2f  = (ushort*)alloc(128 * 64 * 8 * 2);
    ushort* y    = (ushort*)alloc((size_t)N * 256 * 2);           // 51.2 MB
    float* statsR = (float*)alloc(2 * NREP * 256 * 4);            // 64 KB
    int*   CM    = (int*)alloc((size_t)NB * nchunk * 4);          // 612 KB
    int*   PO    = (int*)alloc((size_t)NB * nchunk * 4);          // 612 KB
    int*   BT    = (int*)alloc(256 * 4);
    uint2* tmp2  = (uint2*)alloc((size_t)E * 8);                  // 12.8 MB
    unsigned int* ewp = (unsigned int*)alloc(((size_t)E + 8) * 4);// 6.4 MB
    int*   offs  = (int*)alloc((size_t)(N + 1) * 4);              // 400 KB

    // init: hfrag (64 blocks) + zero statsR (16 blocks)
    k_init<<<80, 256, 0, stream>>>(w1, w2, h1f, h2f, statsR);
    // CSR build, LDS-atomic only
    k_p1<<<nchunk, 256, 0, stream>>>(rows, CM, E, nchunk, NB);
    k_p2<<<NB, 256, 0, stream>>>(CM, PO, BT, nchunk);
    k_p3<<<nchunk, 256, 0, stream>>>(rows, cols, evin, PO, BT, tmp2, E, nchunk, NB);
    k_p4<<<NB, 1024, 0, stream>>>(tmp2, BT, ewp, offs, N, NB);

    int gblk = (N + 127) / 128;  // 782
    // y = x @ H1 (bf16)
    k_gemm1<<<gblk, 256, 0, stream>>>(x, h1f, y, N);
    // out1(bf16, interleaved in d_out) = segsum(ev * y[col]) + BN stats
    k_spmm<<<(N + 7) / 8, 256, 0, stream>>>(y, offs, ewp, (ushort*)out, statsR, N);
    // d_out(f32) = tanh(BN(out1)) @ H2
    k_gemm2<<<gblk, 256, 0, stream>>>(out, h2f, statsR, gamma, beta, N);
}